// Round 8
// baseline (234.466 us; speedup 1.0000x reference)
//
#include <hip/hip_runtime.h>
#include <math.h>

// Dims fixed by reference setup_inputs():
//   x   : (NS=1024, NN=192) f32 in {-1,+1}
//   W2  : (DD=24)           f32
//   W3  : (DD, DD)          f32
//   phi : (NN, 2)           f32
//   nd  : (NN, NN)          i32 in [0, DD), SYMMETRIC
// out  : (NS,) f32 = J2 + J3 + logmf
//
// c[j,r] = sum_i x_i [nd[j,i]==r] = 2*popc(M[j][r] & P[n]) - popc(M[j][r])
// out[n] = sum_j [ x_j*(0.5*<c_j,W2> + c_j^T W3 c_j) + log(phi[j, x_j>0]) ]
//
// K1: grid (16,24), 512 thr. Quad form uses LDS-staged symmetric
//     Qx[r][s]=W3[r][s]+W3[s][r] (col 24 = W2[r]); rows read via b128
//     broadcast ds_reads -> no per-wave scalar-load storm.
//     q = 0.5 * c^T Qx c  ==  c^T W3 c.
// K2: out[n] = sum_g partial[g][n].

#define NS 1024
#define NN 192
#define DD 24
#define QS 28   // Qx row stride in floats (112 B, 16B-aligned)

typedef unsigned long long ull;

__global__ __launch_bounds__(512) void fused_kernel(
    const float* __restrict__ x,
    const float* __restrict__ W2,
    const float* __restrict__ W3,
    const float* __restrict__ phi,
    const int*   __restrict__ nd,
    float* __restrict__ partial)    // ws: [24][NS] f32
{
    const int tid  = threadIdx.x;
    const int lane = tid & 63;
    const int wv   = tid >> 6;          // 0..7
    const int n0   = blockIdx.x * 64;
    const int by   = blockIdx.y;
    const int j    = by * 8 + wv;       // wave-uniform

    __shared__ unsigned Pp[64][6];      // sign bits per sample
    __shared__ unsigned Msk[8][24][8];  // per-j,r: 6 mask words, [6]=-(float)cnt
    __shared__ float    Qx[DD][QS];     // symmetrized W3, col 24 = W2
    __shared__ float    part[8][64];

    // ---- stage Qx = W3 + W3^T (cols 0..23), W2 (col 24) ----
    for (int idx = tid; idx < DD * DD; idx += 512) {
        const int r = idx / DD, s = idx - r * DD;
        Qx[r][s] = W3[r * DD + s] + W3[s * DD + r];
    }
    if (tid < DD) Qx[tid][24] = W2[tid];

    // ---- Phase A: wave wv packs samples wv*8 .. wv*8+7 ----
    #pragma unroll
    for (int q = 0; q < 8; ++q) {
        const int s = wv * 8 + q;
        const float* xr = &x[(size_t)(n0 + s) * NN];
        unsigned keep = 0;
        #pragma unroll
        for (int c = 0; c < 3; ++c) {
            const float v = xr[c * 64 + lane];
            const ull m = __ballot(v > 0.0f);
            const unsigned lo = (unsigned)m, hi = (unsigned)(m >> 32);
            if (lane == 2 * c)     keep = lo;
            if (lane == 2 * c + 1) keep = hi;
        }
        if (lane < 6) Pp[s][lane] = keep;
    }

    // ---- Phase B: masks for this wave's j ----
    {
        const int* ndr = &nd[(size_t)j * NN];
        #pragma unroll
        for (int c = 0; c < 3; ++c) {
            const int ndv = ndr[c * 64 + lane];
            unsigned wlo = 0, whi = 0;
            #pragma unroll
            for (int r = 0; r < DD; ++r) {
                const ull m = __ballot(ndv == r);
                if (lane == r) { wlo = (unsigned)m; whi = (unsigned)(m >> 32); }
            }
            if (lane < DD) {
                Msk[wv][lane][2 * c]     = wlo;
                Msk[wv][lane][2 * c + 1] = whi;
            }
        }
    }
    __syncthreads();

    // ---- Phase B2: negated popcounts (one thread per (j_local, r)) ----
    if (tid < 8 * DD) {
        const int jl = tid / DD, r = tid % DD;
        int cnt = 0;
        #pragma unroll
        for (int w = 0; w < 6; ++w) cnt += __popc(Msk[jl][r][w]);
        Msk[jl][r][6] = __float_as_uint(-(float)cnt);
    }
    __syncthreads();

    // ---- Phase C ----
    const unsigned p0 = Pp[lane][0], p1 = Pp[lane][1], p2 = Pp[lane][2];
    const unsigned p3 = Pp[lane][3], p4 = Pp[lane][4], p5 = Pp[lane][5];

    float c[DD];
    #pragma unroll
    for (int r = 0; r < DD; ++r) {
        const unsigned m0 = Msk[wv][r][0], m1 = Msk[wv][r][1], m2 = Msk[wv][r][2];
        const unsigned m3 = Msk[wv][r][3], m4 = Msk[wv][r][4], m5 = Msk[wv][r][5];
        const float ncnt  = __uint_as_float(Msk[wv][r][6]);
        const int pc = __popc(m0 & p0) + __popc(m1 & p1) + __popc(m2 & p2)
                     + __popc(m3 & p3) + __popc(m4 & p4) + __popc(m5 & p5);
        c[r] = fmaf(2.0f, (float)pc, ncnt);
    }

    // quad form via LDS Qx rows (broadcast b128 reads, 4 accumulators)
    float qf = 0.0f, l2 = 0.0f;
    #pragma unroll
    for (int r = 0; r < DD; ++r) {
        const float4* qrow = reinterpret_cast<const float4*>(&Qx[r][0]);
        const float4 a = qrow[0], b = qrow[1], d = qrow[2];
        const float4 e = qrow[3], f = qrow[4], g = qrow[5];
        float t0 = a.x * c[0]  + a.y * c[1]  + a.z * c[2]  + a.w * c[3];
        float t1 = b.x * c[4]  + b.y * c[5]  + b.z * c[6]  + b.w * c[7];
        float t2 = d.x * c[8]  + d.y * c[9]  + d.z * c[10] + d.w * c[11];
        float t3 = e.x * c[12] + e.y * c[13] + e.z * c[14] + e.w * c[15];
        t0 = fmaf(f.x, c[16], fmaf(f.y, c[17], fmaf(f.z, c[18], fmaf(f.w, c[19], t0))));
        t1 = fmaf(g.x, c[20], fmaf(g.y, c[21], fmaf(g.z, c[22], fmaf(g.w, c[23], t1))));
        const float t = (t0 + t1) + (t2 + t3);
        qf = fmaf(c[r], t, qf);
        l2 = fmaf(Qx[r][24], c[r], l2);   // W2[r]
    }

    // sign of x[n, j] = bit j of P; phi-log folded in per (n, j)
    const int w = j >> 5, bpos = j & 31;
    unsigned pw = (w == 0) ? p0 : (w == 1) ? p1 : (w == 2) ? p2
                : (w == 3) ? p3 : (w == 4) ? p4 : p5;
    const int   pos = (int)((pw >> bpos) & 1u);
    const float xj  = pos ? 1.0f : -1.0f;
    const float lp0 = logf(phi[j * 2 + 0]);
    const float lp1 = logf(phi[j * 2 + 1]);

    // 0.5*(l2 + c^T Qx c) = 0.5*<c,W2> + c^T W3 c
    const float acc = xj * 0.5f * (l2 + qf) + (pos ? lp1 : lp0);

    part[wv][lane] = acc;
    __syncthreads();
    if (wv == 0) {
        float s = part[0][lane] + part[1][lane] + part[2][lane] + part[3][lane]
                + part[4][lane] + part[5][lane] + part[6][lane] + part[7][lane];
        partial[by * NS + n0 + lane] = s;   // plain store, no atomic
    }
}

__global__ __launch_bounds__(256) void reduce_kernel(
    const float* __restrict__ partial,   // [24][NS]
    float* __restrict__ out)             // [NS]
{
    const int n = blockIdx.x * 256 + threadIdx.x;
    float s = 0.0f;
    #pragma unroll
    for (int g = 0; g < 24; ++g) s += partial[g * NS + n];  // coalesced per g
    out[n] = s;
}

extern "C" void kernel_launch(void* const* d_in, const int* in_sizes, int n_in,
                              void* d_out, int out_size, void* d_ws, size_t ws_size,
                              hipStream_t stream) {
    const float* x   = (const float*)d_in[0];
    const float* W2  = (const float*)d_in[1];
    const float* W3  = (const float*)d_in[2];
    const float* phi = (const float*)d_in[3];
    const int*   nd  = (const int*)d_in[4];
    float* out = (float*)d_out;
    float* partial = (float*)d_ws;   // 24*NS*4 = 96 KB

    const int ns = in_sizes[0] / NN;   // 1024
    fused_kernel<<<dim3(ns / 64, NN / 8), 512, 0, stream>>>(x, W2, W3, phi, nd, partial);
    reduce_kernel<<<ns / 256, 256, 0, stream>>>(partial, out);
}

// Round 9
// 26.199 us; speedup vs baseline: 8.9494x; 8.9494x over previous
//
#include <hip/hip_runtime.h>
#include <math.h>

// Dims fixed by reference setup_inputs():
//   x   : (NS=1024, NN=192) f32 in {-1,+1}
//   W2  : (DD=24)           f32
//   W3  : (DD, DD)          f32
//   phi : (NN, 2)           f32
//   nd  : (NN, NN)          i32 in [0, DD), SYMMETRIC
// out  : (NS,) f32 = J2 + J3 + logmf
//
// R1 structure (best measured: single node, block = one sample, 192 thr,
// thread j owns LDS histogram row c_j), with the quadratic form switched to
// a triangular symmetrized Q staged once in LDS:
//   Q[r][r] = W3[r][r]; Q[r][s>r] = W3[r][s] + W3[s][r]; Q[r][24] = W2[r]
//   c^T W3 c = sum_r c_r * (Q[r][r] c_r + sum_{s>r} Q[r][s] c_s)
// -> 324 broadcast ds_read_b32 + ~350 FMA instead of 576 + 576.
// No float4 (R8 spill lesson), no second node, no atomics, no memsets.

#define NS   1024
#define NN   192
#define DD   24
#define CPAD 25   // histogram row stride: odd -> spreads banks

__global__ __launch_bounds__(192) void jmf3_kernel(
    const float* __restrict__ x,    // (NS, NN)
    const float* __restrict__ W2,   // (DD)
    const float* __restrict__ W3,   // (DD, DD)
    const float* __restrict__ phi,  // (NN, 2)
    const int*   __restrict__ nd,   // (NN, NN)
    float* __restrict__ out)        // (NS)
{
    __shared__ float sx[NN];
    __shared__ float sQ[DD][CPAD];  // triangular symmetrized W3; col 24 = W2
    __shared__ float sc[NN * CPAD]; // per-thread histogram rows
    __shared__ float red[3];

    const int tid = threadIdx.x;    // 0..191
    const int n   = blockIdx.x;     // sample

    // ---- stage inputs ----
    sx[tid] = x[n * NN + tid];
    for (int idx = tid; idx < DD * DD; idx += NN) {
        const int r = idx / DD, s = idx - r * DD;
        float v = 0.0f;
        if (s > r)       v = W3[r * DD + s] + W3[s * DD + r];
        else if (s == r) v = W3[r * DD + r];
        sQ[r][s] = v;
    }
    if (tid < DD) sQ[tid][DD] = W2[tid];
    #pragma unroll
    for (int r = 0; r < CPAD; ++r) sc[tid * CPAD + r] = 0.0f;
    __syncthreads();

    // ---- per-column histogram: thread tid owns column j = tid ----
    const int j = tid;
    float* cj = &sc[j * CPAD];
    for (int i = 0; i < NN; ++i) {
        const int r = nd[i * NN + j];   // coalesced across lanes
        cj[r] += sx[i];                 // private row, broadcast sx read
    }

    float c[DD];
    #pragma unroll
    for (int r = 0; r < DD; ++r) c[r] = cj[r];

    // ---- triangular quadratic form q = c^T W3 c and l2 = <c, W2> ----
    float q = 0.0f, l2 = 0.0f;
    #pragma unroll
    for (int r = 0; r < DD; ++r) {
        float t = sQ[r][r] * c[r];
        #pragma unroll
        for (int s = r + 1; s < DD; ++s) t = fmaf(sQ[r][s], c[s], t);
        q  = fmaf(c[r], t, q);
        l2 = fmaf(sQ[r][DD], c[r], l2);
    }

    const float xj  = sx[j];
    const int   idx = (xj > 0.0f) ? 1 : 0;
    const float contrib = xj * fmaf(0.5f, l2, q) + logf(phi[j * 2 + idx]);

    // ---- block reduction: 3 waves of 64 ----
    float v = contrib;
    #pragma unroll
    for (int off = 32; off >= 1; off >>= 1)
        v += __shfl_down(v, off, 64);
    const int wave = tid >> 6;
    if ((tid & 63) == 0) red[wave] = v;
    __syncthreads();
    if (tid == 0) out[n] = red[0] + red[1] + red[2];
}

extern "C" void kernel_launch(void* const* d_in, const int* in_sizes, int n_in,
                              void* d_out, int out_size, void* d_ws, size_t ws_size,
                              hipStream_t stream) {
    const float* x   = (const float*)d_in[0];
    const float* W2  = (const float*)d_in[1];
    const float* W3  = (const float*)d_in[2];
    const float* phi = (const float*)d_in[3];
    const int*   nd  = (const int*)d_in[4];
    float* out = (float*)d_out;

    const int ns = in_sizes[0] / NN;   // 1024
    jmf3_kernel<<<ns, NN, 0, stream>>>(x, W2, W3, phi, nd, out);
}